// Round 3
// baseline (1055.998 us; speedup 1.0000x reference)
//
#include <hip/hip_runtime.h>
#include <float.h>

// Problem constants (match reference)
constexpr int H = 1024, W = 1024, C = 128, N_ITER = 8;
constexpr int TPB = 256;          // threads per block
constexpr int TILE = 32;          // 32x32 pixel tile per block
constexpr int PPT = 4;            // pixels (consecutive cols) per thread
constexpr int K = 32;             // atomic shards (contention depth 1024/K = 32)
constexpr int SLOTS = 2 * C;      // 256 accumulator slots
constexpr int NBLK = (H / TILE) * (W / TILE);   // 1024 blocks
constexpr int NCNT = 128;         // barrier arrival counters (depth 8 each)
constexpr int CNT_STRIDE = 16;    // ints between counters (64B apart)
constexpr int ARRIVE_DEPTH = NBLK / NCNT;       // 8

// Round-3 lesson: atomic-contention-bound -> 32-way sharding (kept).
//   (depth-1024 same-address RMW ~= 43us -> ~100cy per same-address RMW;
//    this sizes both the output shards and the barrier arrival counters.)
// Round-4 lesson: O(C) dependent-LDS dedup chain -> all-pairs scan (kept).
// Round-5 lesson: fusing 9 dispatches into one cooperative kernel removed
//   ~11us/dispatch overhead, BUT the barrier wait side (128 acquire-spinning
//   lanes per block, s_sleep(1)) flooded the coherent fabric with ~1e6
//   invalidating loads/us -> congestion collapse, 892us dispatch (VALUBusy
//   3.2% == only ~28us of real work).
// Round-6 (this round): two-level low-traffic barrier.
//   Arrive: tid0 release-fetch_add on counter[bid&127]  (depth 8, ~0.3us).
//   Aggregate: block 0's 128 lanes poll the 128 counters RELAXED + s_sleep,
//     then lane 0 acquire-fences and release-publishes flags[it].
//   Wait: ONE lane per other block polls flags[it] RELAXED + s_sleep(8)
//     (read-only, same line, no invalidates), then one __threadfence()
//     (acquire) per block before reading prev shards.
//   happens-before: worker rel-add -> blk0 acq -> blk0 rel-store flag ->
//   worker relaxed-load + acq-fence  (transitive release/acquire chain).
__global__ __launch_bounds__(TPB) void kmeans_fused(
    const float* __restrict__ cur0,        // [SLOTS] input clusters
    const float* __restrict__ heatmap,     // [H,W]
    float* __restrict__ shards,            // [N_ITER][K][SLOTS] (pre-zeroed)
    int*   __restrict__ barCnt,            // [N_ITER][NCNT*CNT_STRIDE] (pre-zeroed)
    int*   __restrict__ flags,             // [N_ITER*CNT_STRIDE] (pre-zeroed)
    float* __restrict__ out)               // [SLOTS]
{
    __shared__ float2 cls[C];              // aliased as float[SLOTS]
    __shared__ float2 cand[C];
    __shared__ int    candIdx[C];
    __shared__ float  waveMin[2];
    __shared__ int    waveCnt[2];
    __shared__ float  acc[SLOTS];          // SLOTS == 256 == TPB
    __shared__ unsigned char dupf[C];      // 1 = has a lower-indexed twin

    const int tid   = threadIdx.x;
    const int bid   = blockIdx.x;
    const int tileR = (bid >> 5) * TILE;
    const int tileC = (bid & 31) * TILE;

    // ---- one-time pixel setup (amortized over 8 iters) ----
    const int   rowIn = tid >> 3;                         // 0..31
    const float fr    = (float)(tileR + rowIn);
    const int   col0  = tileC + (tid & 7) * PPT;
    const float4 h4   = *(const float4*)(heatmap + (size_t)(tileR + rowIn) * W + col0);
    float hval[PPT] = { h4.x, h4.y, h4.z, h4.w };
    float colf[PPT];
#pragma unroll
    for (int p = 0; p < PPT; ++p) colf[p] = (float)(col0 + p);

    for (int it = 0; it < N_ITER; ++it) {
        float* outS = shards + (size_t)it * K * SLOTS;

        // ---- phase 0: materialize current cluster coords into LDS ----
        float coord;
        if (it == 0) {
            coord = cur0[tid];
        } else {
            const float* prevS = shards + (size_t)(it - 1) * K * SLOTS;
            float s = 0.0f;
#pragma unroll
            for (int k = 0; k < K; ++k) s += prevS[k * SLOTS + tid];
            coord = s;
        }
        acc[tid] = 0.0f;
        if (tid < C) dupf[tid] = 0;
        ((float*)cls)[tid] = coord;
        __syncthreads();

        // ---- phase 1a: center-distance + wave min (threads 0..127)
        //      concurrently: all-pairs coincidence scan (all 256 threads) ----
        const int    di  = tid & (C - 1);
        const float2 dme = cls[di];

        float dcen = 0.0f;
        if (tid < C) {
            const float dxr = dme.x - ((float)tileR + 15.5f);
            const float dyc = dme.y - ((float)tileC + 15.5f);
            dcen = sqrtf(dxr * dxr + dyc * dyc);
            float m = dcen;
#pragma unroll
            for (int off = 32; off > 0; off >>= 1)
                m = fminf(m, __shfl_xor(m, off));
            if ((tid & 63) == 0) waveMin[tid >> 6] = m;
        }

        {
            // pairs (di,(di+k)&127): k=1..32 on waves 0/1, k=33..64 on waves 2/3.
            const int kLo = (tid < C) ? 1 : 33;
#pragma unroll 8
            for (int kk = 0; kk < 32; ++kk) {
                const int k = kLo + kk;
                const int j = (di + k) & (C - 1);
                const float2 o = cls[j];
                if (o.x == dme.x && o.y == dme.y)
                    dupf[(di + k < C) ? (di + k) : di] = 1;  // mark HIGHER index
            }
        }
        __syncthreads();

        // ---- phase 1b: prune + dedup-flag + ballot prefix (order-preserving) ----
        bool keep = false;
        int  pre  = 0;
        if (tid < C) {
            // 2*r_tile = 2*15.5*sqrt(2) = 43.84062; +1.0 clamp/rounding margin
            const float thr = fminf(waveMin[0], waveMin[1]) + 44.84062f;
            keep = (dcen <= thr) && (dupf[tid] == 0);
            const unsigned long long mask = __ballot(keep);
            const int lane = tid & 63;
            pre = __popcll(mask & ((1ull << lane) - 1ull));
            if (lane == 0) waveCnt[tid >> 6] = __popcll(mask);
        }
        __syncthreads();
        if (keep) {
            const int pos = pre + ((tid >= 64) ? waveCnt[0] : 0);
            cand[pos]    = cls[tid];
            candIdx[pos] = tid;
        }
        __syncthreads();

        const int nCand = waveCnt[0] + waveCnt[1];   // >= 1 always

        // ---- phase 2: pruned argmin over candidates ----
        float best[PPT];
        int   bi[PPT];
#pragma unroll
        for (int p = 0; p < PPT; ++p) { best[p] = FLT_MAX; bi[p] = 0; }

        for (int k = 0; k < nCand; ++k) {
            const float2 cl = cand[k];                    // wave-uniform broadcast
            const int    ci = candIdx[k];
            const float  dx  = fr - cl.x;
            const float  dx2 = dx * dx;                   // row-constant, reused x4
#pragma unroll
            for (int p = 0; p < PPT; ++p) {
                const float dy  = colf[p] - cl.y;
                const float d2  = fmaf(dy, dy, dx2);
                const float key = fmaxf(d2, 1.0f);        // clamp before compare
                const bool  lt  = key < best[p];          // strict <: first-index ties
                bi[p]   = lt ? ci  : bi[p];
                best[p] = lt ? key : best[p];
            }
        }

        // ---- epilogue: wave-uniform reduce fast path; LDS scatter ----
#pragma unroll
        for (int p = 0; p < PPT; ++p) {
            const float bd  = fmaxf(1.0f, sqrtf(best[p]));  // = max(1, sqrt(d2))
            const float wgt = hval[p] / bd;
            float v0 = fr      * wgt;
            float v1 = colf[p] * wgt;
            const int b0 = __shfl(bi[p], 0);
            if (__ballot(bi[p] == b0) == 0xFFFFFFFFFFFFFFFFull) {
#pragma unroll
                for (int off = 32; off > 0; off >>= 1) {
                    v0 += __shfl_xor(v0, off);
                    v1 += __shfl_xor(v1, off);
                }
                if ((tid & 63) == 0) {
                    unsafeAtomicAdd(&acc[2 * b0 + 0], v0);
                    unsafeAtomicAdd(&acc[2 * b0 + 1], v1);
                }
            } else {
                unsafeAtomicAdd(&acc[2 * bi[p] + 0], v0);
                unsafeAtomicAdd(&acc[2 * bi[p] + 1], v1);
            }
        }
        __syncthreads();

        // one global atomic per NONZERO slot into this block's shard.
        const float a = acc[tid];
        if (a != 0.0f)
            unsafeAtomicAdd(&outS[(bid & (K - 1)) * SLOTS + tid], a);

        // ---- two-level grid barrier (per-iteration counters + flag) ----
        __threadfence();                       // release: drain my shard atomics
        __syncthreads();
        if (tid == 0) {
            int* cnt = barCnt + ((size_t)it * NCNT + (bid & (NCNT - 1))) * CNT_STRIDE;
            __hip_atomic_fetch_add(cnt, 1, __ATOMIC_RELEASE, __HIP_MEMORY_SCOPE_AGENT);
        }
        const bool lastIter = (it == N_ITER - 1);
        if (bid == 0) {
            // aggregate: 128 lanes poll 128 counters (relaxed, low rate)
            if (tid < NCNT) {
                const int* cptr = barCnt + ((size_t)it * NCNT + tid) * CNT_STRIDE;
                while (__hip_atomic_load(cptr, __ATOMIC_RELAXED,
                                         __HIP_MEMORY_SCOPE_AGENT) < ARRIVE_DEPTH)
                    __builtin_amdgcn_s_sleep(2);
            }
            __syncthreads();
            if (tid == 0) {
                __threadfence();               // acquire workers' releases
                __hip_atomic_store(flags + (size_t)it * CNT_STRIDE, 1,
                                   __ATOMIC_RELEASE, __HIP_MEMORY_SCOPE_AGENT);
            }
            __syncthreads();
            __threadfence();                   // acquire for next phase-0 loads
        } else if (!lastIter) {
            // wait: ONE relaxed poller per block, no invalidates in the loop
            if (tid == 0) {
                const int* fptr = flags + (size_t)it * CNT_STRIDE;
                while (__hip_atomic_load(fptr, __ATOMIC_RELAXED,
                                         __HIP_MEMORY_SCOPE_AGENT) == 0)
                    __builtin_amdgcn_s_sleep(8);
            }
            __syncthreads();
            __threadfence();                   // acquire for next phase-0 loads
        }
        // last iteration: non-zero blocks arrive and exit without waiting
    }

    // ---- finalize (block 0 only; it aggregated the last barrier) ----
    if (bid == 0) {
        const float* last = shards + (size_t)(N_ITER - 1) * K * SLOTS;
        float s = 0.0f;
#pragma unroll
        for (int k = 0; k < K; ++k) s += last[k * SLOTS + tid];
        out[tid] = s;
    }
}

// ---------------- fallback path (if cooperative launch unavailable) ----------------
__global__ __launch_bounds__(TPB) void kmeans_step(
    const float* __restrict__ cur0,
    const float* __restrict__ prevShards,
    const float* __restrict__ heatmap,
    float* __restrict__ outShards)
{
    __shared__ float2 cls[C];
    __shared__ float2 cand[C];
    __shared__ int    candIdx[C];
    __shared__ float  waveMin[2];
    __shared__ int    waveCnt[2];
    __shared__ float  acc[SLOTS];
    __shared__ unsigned char dupf[C];

    const int tid   = threadIdx.x;
    const int tileR = (blockIdx.x >> 5) * TILE;
    const int tileC = (blockIdx.x & 31) * TILE;

    acc[tid] = 0.0f;
    if (tid < C) dupf[tid] = 0;

    float coord;
    if (prevShards) {
        float s = 0.0f;
#pragma unroll
        for (int k = 0; k < K; ++k) s += prevShards[k * SLOTS + tid];
        coord = s;
    } else {
        coord = cur0[tid];
    }
    ((float*)cls)[tid] = coord;
    __syncthreads();

    const int    di  = tid & (C - 1);
    const float2 dme = cls[di];

    float dcen = 0.0f;
    if (tid < C) {
        const float dxr = dme.x - ((float)tileR + 15.5f);
        const float dyc = dme.y - ((float)tileC + 15.5f);
        dcen = sqrtf(dxr * dxr + dyc * dyc);
        float m = dcen;
#pragma unroll
        for (int off = 32; off > 0; off >>= 1)
            m = fminf(m, __shfl_xor(m, off));
        if ((tid & 63) == 0) waveMin[tid >> 6] = m;
    }
    {
        const int kLo = (tid < C) ? 1 : 33;
#pragma unroll 8
        for (int kk = 0; kk < 32; ++kk) {
            const int k = kLo + kk;
            const int j = (di + k) & (C - 1);
            const float2 o = cls[j];
            if (o.x == dme.x && o.y == dme.y)
                dupf[(di + k < C) ? (di + k) : di] = 1;
        }
    }
    __syncthreads();

    bool keep = false;
    int  pre  = 0;
    if (tid < C) {
        const float thr = fminf(waveMin[0], waveMin[1]) + 44.84062f;
        keep = (dcen <= thr) && (dupf[tid] == 0);
        const unsigned long long mask = __ballot(keep);
        const int lane = tid & 63;
        pre = __popcll(mask & ((1ull << lane) - 1ull));
        if (lane == 0) waveCnt[tid >> 6] = __popcll(mask);
    }
    __syncthreads();
    if (keep) {
        const int pos = pre + ((tid >= 64) ? waveCnt[0] : 0);
        cand[pos]    = cls[tid];
        candIdx[pos] = tid;
    }
    __syncthreads();

    const int nCand = waveCnt[0] + waveCnt[1];

    const int   rowIn = tid >> 3;
    const float fr    = (float)(tileR + rowIn);
    const int   col0  = tileC + (tid & 7) * PPT;
    const float4 h4   = *(const float4*)(heatmap + (size_t)(tileR + rowIn) * W + col0);

    float hval[PPT] = { h4.x, h4.y, h4.z, h4.w };
    float colf[PPT], best[PPT];
    int   bi[PPT];
#pragma unroll
    for (int p = 0; p < PPT; ++p) {
        colf[p] = (float)(col0 + p);
        best[p] = FLT_MAX;
        bi[p]   = 0;
    }

    for (int k = 0; k < nCand; ++k) {
        const float2 cl = cand[k];
        const int    ci = candIdx[k];
        const float  dx  = fr - cl.x;
        const float  dx2 = dx * dx;
#pragma unroll
        for (int p = 0; p < PPT; ++p) {
            const float dy  = colf[p] - cl.y;
            const float d2  = fmaf(dy, dy, dx2);
            const float key = fmaxf(d2, 1.0f);
            const bool  lt  = key < best[p];
            bi[p]   = lt ? ci  : bi[p];
            best[p] = lt ? key : best[p];
        }
    }

#pragma unroll
    for (int p = 0; p < PPT; ++p) {
        const float bd  = fmaxf(1.0f, sqrtf(best[p]));
        const float wgt = hval[p] / bd;
        float v0 = fr      * wgt;
        float v1 = colf[p] * wgt;
        const int b0 = __shfl(bi[p], 0);
        if (__ballot(bi[p] == b0) == 0xFFFFFFFFFFFFFFFFull) {
#pragma unroll
            for (int off = 32; off > 0; off >>= 1) {
                v0 += __shfl_xor(v0, off);
                v1 += __shfl_xor(v1, off);
            }
            if ((tid & 63) == 0) {
                unsafeAtomicAdd(&acc[2 * b0 + 0], v0);
                unsafeAtomicAdd(&acc[2 * b0 + 1], v1);
            }
        } else {
            unsafeAtomicAdd(&acc[2 * bi[p] + 0], v0);
            unsafeAtomicAdd(&acc[2 * bi[p] + 1], v1);
        }
    }
    __syncthreads();

    const float a = acc[tid];
    if (a != 0.0f)
        unsafeAtomicAdd(&outShards[(blockIdx.x & (K - 1)) * SLOTS + tid], a);
}

__global__ __launch_bounds__(SLOTS) void kmeans_finalize(
    const float* __restrict__ shards,
    float* __restrict__ out)
{
    const int tid = threadIdx.x;
    float s = 0.0f;
#pragma unroll
    for (int k = 0; k < K; ++k) s += shards[k * SLOTS + tid];
    out[tid] = s;
}

extern "C" void kernel_launch(void* const* d_in, const int* in_sizes, int n_in,
                              void* d_out, int out_size, void* d_ws, size_t ws_size,
                              hipStream_t stream) {
    const float* clusters = (const float*)d_in[0];  // [C,2] = 256 floats
    const float* heatmap  = (const float*)d_in[1];  // [H,W] = 1M floats
    float* out = (float*)d_out;                     // [C,2] = 256 floats

    // d_ws layout: [N_ITER][K][SLOTS] shard floats (256 KB),
    //              [N_ITER][NCNT*CNT_STRIDE] barrier ints (64 KB),
    //              [N_ITER*CNT_STRIDE] flag ints (512 B)
    float* shards = (float*)d_ws;
    const size_t shardBytes = (size_t)N_ITER * K * SLOTS * sizeof(float);
    int* barCnt = (int*)((char*)d_ws + shardBytes);
    const size_t cntBytes = (size_t)N_ITER * NCNT * CNT_STRIDE * sizeof(int);
    int* flags = (int*)((char*)barCnt + cntBytes);
    const size_t flagBytes = (size_t)N_ITER * CNT_STRIDE * sizeof(int);

    // zero shards + barrier state (harness re-poisons d_ws before every launch)
    hipMemsetAsync(d_ws, 0, shardBytes + cntBytes + flagBytes, stream);

    void* kargs[] = { (void*)&clusters, (void*)&heatmap, (void*)&shards,
                      (void*)&barCnt,   (void*)&flags,   (void*)&out };
    hipError_t e = hipLaunchCooperativeKernel((const void*)kmeans_fused,
                                              dim3(NBLK), dim3(TPB),
                                              kargs, 0, stream);
    if (e != hipSuccess) {
        (void)hipGetLastError();   // clear sticky error; use multi-dispatch fallback
        const size_t perIter = (size_t)K * SLOTS;
        for (int it = 0; it < N_ITER; ++it) {
            const float* prev = (it == 0) ? nullptr : (shards + (it - 1) * perIter);
            float* dst = shards + it * perIter;
            kmeans_step<<<NBLK, TPB, 0, stream>>>(clusters, prev, heatmap, dst);
        }
        kmeans_finalize<<<1, SLOTS, 0, stream>>>(shards + (N_ITER - 1) * perIter, out);
    }
}

// Round 4
// 174.880 us; speedup vs baseline: 6.0384x; 6.0384x over previous
//
#include <hip/hip_runtime.h>
#include <float.h>

// Problem constants (match reference)
constexpr int H = 1024, W = 1024, C = 128, N_ITER = 8;
constexpr int TPB = 256;          // threads per block
constexpr int TILE = 32;          // 32x32 pixel tile per block
constexpr int PPT = 4;            // pixels (consecutive cols) per thread
constexpr int K = 32;             // atomic shards (contention depth 1024/K = 32)
constexpr int SLOTS = 2 * C;      // 256 accumulator slots
constexpr int NBLK = (H / TILE) * (W / TILE);   // 1024 blocks
constexpr int NCNT = 128;         // barrier arrival counters (depth 8 each)
constexpr int CNT_STRIDE = 16;    // ints between counters (64B apart)
constexpr int ARRIVE_DEPTH = NBLK / NCNT;       // 8

// Round-3 lesson: atomic-contention-bound -> 32-way output sharding (kept).
// Round-4 lesson: O(C) dependent-LDS dedup chain -> all-pairs scan (kept).
// Round-5/6 lesson: grid-barrier congestion collapse. BOTH barrier designs
//   kept ~131K polling lanes; agent-scope polls bypass caches, so every poll
//   is an Infinity-Fabric transaction: ~256 tx/cycle >> fabric service rate.
//   Arrivals queue behind spin traffic -> 880-983us regardless of load
//   ordering semantics. Per-block __threadfence() (wbl2+inv x2048/iter) was
//   a secondary invariant cost.
// Round-7 (this round): fence-free, low-poller barrier.
//   - ONE polling lane per worker block (flags), 128 lanes only on block 0
//     (counters): ~300x less fabric poll traffic.
//   - ZERO __threadfence(): shard writes are device-scope atomics performed
//     at the coherence point (measured m20); ordering = s_waitcnt vmcnt(0)
//     [my atomics ack'd at IF] + s_barrier, then RELAXED agent arrive-add
//     (issued after acks -> physically ordered). No wbl2/inv anywhere.
//   - Readers bypass stale L1/L2 with agent-scope atomic loads; block 0's
//     32-shard sum uses grouped sc0 sc1 inline-asm loads (8 in flight).
//   - Block 0 sums shards ONCE (exact k-ascending order, bit-identical) and
//     publishes 256 coords to clsPub[it]; workers read 1 value/thread
//     (32x less phase-0 fabric traffic). Finalize folds into block 0.
__device__ __forceinline__ void waitVmem() {
    asm volatile("s_waitcnt vmcnt(0)" ::: "memory");
}

// Sum base[k*SLOTS + tid], k = 0..31, ascending order (bit-identical to the
// original per-block loop), with cache-bypassing loads, 8 in flight.
__device__ __forceinline__ float sum32_if(const float* base, int tid) {
    const float* p = base + tid;
    float s = 0.0f;
#pragma unroll
    for (int g = 0; g < 4; ++g) {
        const float* q = p + (size_t)g * 8 * SLOTS;
        float a0, a1, a2, a3, a4, a5, a6, a7;
        asm volatile(
            "global_load_dword %0, %8, off sc0 sc1\n\t"
            "global_load_dword %1, %9, off sc0 sc1\n\t"
            "global_load_dword %2, %10, off sc0 sc1\n\t"
            "global_load_dword %3, %11, off sc0 sc1\n\t"
            "global_load_dword %4, %12, off sc0 sc1\n\t"
            "global_load_dword %5, %13, off sc0 sc1\n\t"
            "global_load_dword %6, %14, off sc0 sc1\n\t"
            "global_load_dword %7, %15, off sc0 sc1\n\t"
            "s_waitcnt vmcnt(0)"
            : "=&v"(a0), "=&v"(a1), "=&v"(a2), "=&v"(a3),
              "=&v"(a4), "=&v"(a5), "=&v"(a6), "=&v"(a7)
            : "v"(q),            "v"(q + SLOTS),     "v"(q + 2 * SLOTS),
              "v"(q + 3 * SLOTS), "v"(q + 4 * SLOTS), "v"(q + 5 * SLOTS),
              "v"(q + 6 * SLOTS), "v"(q + 7 * SLOTS)
            : "memory");
        // sequential adds keep the original k-ascending association
        s = s + a0; s = s + a1; s = s + a2; s = s + a3;
        s = s + a4; s = s + a5; s = s + a6; s = s + a7;
    }
    return s;
}

__global__ __launch_bounds__(TPB) void kmeans_fused(
    const float* __restrict__ cur0,        // [SLOTS] input clusters
    const float* __restrict__ heatmap,     // [H,W]
    float* __restrict__ shards,            // [N_ITER][K][SLOTS] (pre-zeroed)
    int*   __restrict__ barCnt,            // [N_ITER][NCNT*CNT_STRIDE] (pre-zeroed)
    int*   __restrict__ flags,             // [N_ITER][CNT_STRIDE] (pre-zeroed)
    float* __restrict__ clsPub,            // [N_ITER][SLOTS] (pre-zeroed)
    float* __restrict__ out)               // [SLOTS]
{
    __shared__ float2 cls[C];              // aliased as float[SLOTS]
    __shared__ float2 cand[C];
    __shared__ int    candIdx[C];
    __shared__ float  waveMin[2];
    __shared__ int    waveCnt[2];
    __shared__ float  acc[SLOTS];          // SLOTS == 256 == TPB
    __shared__ unsigned char dupf[C];      // 1 = has a lower-indexed twin

    const int tid   = threadIdx.x;
    const int bid   = blockIdx.x;
    const int tileR = (bid >> 5) * TILE;
    const int tileC = (bid & 31) * TILE;

    // ---- one-time pixel setup (amortized over 8 iters) ----
    const int   rowIn = tid >> 3;                         // 0..31
    const float fr    = (float)(tileR + rowIn);
    const int   col0  = tileC + (tid & 7) * PPT;
    const float4 h4   = *(const float4*)(heatmap + (size_t)(tileR + rowIn) * W + col0);
    float hval[PPT] = { h4.x, h4.y, h4.z, h4.w };
    float colf[PPT];
#pragma unroll
    for (int p = 0; p < PPT; ++p) colf[p] = (float)(col0 + p);

    for (int it = 0; it < N_ITER; ++it) {
        // ---- obtain this iteration's cluster coords ----
        float coord;
        if (it == 0) {
            coord = cur0[tid];
        } else {
            const int prevIt = it - 1;
            if (bid == 0) {
                // aggregate: 128 lanes poll 128 arrival counters (agent loads)
                if (tid < NCNT) {
                    int* cptr = barCnt + ((size_t)prevIt * NCNT + tid) * CNT_STRIDE;
                    while (__hip_atomic_load(cptr, __ATOMIC_RELAXED,
                                             __HIP_MEMORY_SCOPE_AGENT) < ARRIVE_DEPTH)
                        __builtin_amdgcn_s_sleep(2);
                }
                __syncthreads();
                // sum 32 shards (coherence-point data; cache-bypassing loads)
                const float s = sum32_if(shards + (size_t)prevIt * K * SLOTS, tid);
                __hip_atomic_store(clsPub + (size_t)prevIt * SLOTS + tid, s,
                                   __ATOMIC_RELAXED, __HIP_MEMORY_SCOPE_AGENT);
                waitVmem();                       // publish stores ack'd at IF
                __syncthreads();
                if (tid == 0)
                    __hip_atomic_fetch_add(flags + (size_t)prevIt * CNT_STRIDE, 1,
                                           __ATOMIC_RELAXED, __HIP_MEMORY_SCOPE_AGENT);
                coord = s;
            } else {
                // wait: ONE polling lane per block
                if (tid == 0) {
                    int* fptr = flags + (size_t)prevIt * CNT_STRIDE;
                    while (__hip_atomic_load(fptr, __ATOMIC_RELAXED,
                                             __HIP_MEMORY_SCOPE_AGENT) == 0)
                        __builtin_amdgcn_s_sleep(4);
                }
                __syncthreads();
                coord = __hip_atomic_load(clsPub + (size_t)prevIt * SLOTS + tid,
                                          __ATOMIC_RELAXED, __HIP_MEMORY_SCOPE_AGENT);
            }
        }

        // ---- phase 0: coords into LDS ----
        acc[tid] = 0.0f;
        if (tid < C) dupf[tid] = 0;
        ((float*)cls)[tid] = coord;
        __syncthreads();

        // ---- phase 1a: center-distance + wave min (threads 0..127)
        //      concurrently: all-pairs coincidence scan (all 256 threads) ----
        const int    di  = tid & (C - 1);
        const float2 dme = cls[di];

        float dcen = 0.0f;
        if (tid < C) {
            const float dxr = dme.x - ((float)tileR + 15.5f);
            const float dyc = dme.y - ((float)tileC + 15.5f);
            dcen = sqrtf(dxr * dxr + dyc * dyc);
            float m = dcen;
#pragma unroll
            for (int off = 32; off > 0; off >>= 1)
                m = fminf(m, __shfl_xor(m, off));
            if ((tid & 63) == 0) waveMin[tid >> 6] = m;
        }

        {
            // pairs (di,(di+k)&127): k=1..32 on waves 0/1, k=33..64 on waves 2/3.
            const int kLo = (tid < C) ? 1 : 33;
#pragma unroll 8
            for (int kk = 0; kk < 32; ++kk) {
                const int k = kLo + kk;
                const int j = (di + k) & (C - 1);
                const float2 o = cls[j];
                if (o.x == dme.x && o.y == dme.y)
                    dupf[(di + k < C) ? (di + k) : di] = 1;  // mark HIGHER index
            }
        }
        __syncthreads();

        // ---- phase 1b: prune + dedup-flag + ballot prefix (order-preserving) ----
        bool keep = false;
        int  pre  = 0;
        if (tid < C) {
            // 2*r_tile = 2*15.5*sqrt(2) = 43.84062; +1.0 clamp/rounding margin
            const float thr = fminf(waveMin[0], waveMin[1]) + 44.84062f;
            keep = (dcen <= thr) && (dupf[tid] == 0);
            const unsigned long long mask = __ballot(keep);
            const int lane = tid & 63;
            pre = __popcll(mask & ((1ull << lane) - 1ull));
            if (lane == 0) waveCnt[tid >> 6] = __popcll(mask);
        }
        __syncthreads();
        if (keep) {
            const int pos = pre + ((tid >= 64) ? waveCnt[0] : 0);
            cand[pos]    = cls[tid];
            candIdx[pos] = tid;
        }
        __syncthreads();

        const int nCand = waveCnt[0] + waveCnt[1];   // >= 1 always

        // ---- phase 2: pruned argmin over candidates ----
        float best[PPT];
        int   bi[PPT];
#pragma unroll
        for (int p = 0; p < PPT; ++p) { best[p] = FLT_MAX; bi[p] = 0; }

        for (int k = 0; k < nCand; ++k) {
            const float2 cl = cand[k];                    // wave-uniform broadcast
            const int    ci = candIdx[k];
            const float  dx  = fr - cl.x;
            const float  dx2 = dx * dx;                   // row-constant, reused x4
#pragma unroll
            for (int p = 0; p < PPT; ++p) {
                const float dy  = colf[p] - cl.y;
                const float d2  = fmaf(dy, dy, dx2);
                const float key = fmaxf(d2, 1.0f);        // clamp before compare
                const bool  lt  = key < best[p];          // strict <: first-index ties
                bi[p]   = lt ? ci  : bi[p];
                best[p] = lt ? key : best[p];
            }
        }

        // ---- epilogue: wave-uniform reduce fast path; LDS scatter ----
#pragma unroll
        for (int p = 0; p < PPT; ++p) {
            const float bd  = fmaxf(1.0f, sqrtf(best[p]));  // = max(1, sqrt(d2))
            const float wgt = hval[p] / bd;
            float v0 = fr      * wgt;
            float v1 = colf[p] * wgt;
            const int b0 = __shfl(bi[p], 0);
            if (__ballot(bi[p] == b0) == 0xFFFFFFFFFFFFFFFFull) {
#pragma unroll
                for (int off = 32; off > 0; off >>= 1) {
                    v0 += __shfl_xor(v0, off);
                    v1 += __shfl_xor(v1, off);
                }
                if ((tid & 63) == 0) {
                    unsafeAtomicAdd(&acc[2 * b0 + 0], v0);
                    unsafeAtomicAdd(&acc[2 * b0 + 1], v1);
                }
            } else {
                unsafeAtomicAdd(&acc[2 * bi[p] + 0], v0);
                unsafeAtomicAdd(&acc[2 * bi[p] + 1], v1);
            }
        }
        __syncthreads();

        // one global atomic per NONZERO slot into this block's shard.
        // (device-scope atomic, performed at the coherence point — m20)
        const float a = acc[tid];
        if (a != 0.0f)
            unsafeAtomicAdd(&shards[(size_t)it * K * SLOTS
                                    + (bid & (K - 1)) * SLOTS + tid], a);

        // ---- arrive (fence-free): my atomics ack'd, then relaxed add ----
        waitVmem();
        __syncthreads();
        if (tid == 0)
            __hip_atomic_fetch_add(
                barCnt + ((size_t)it * NCNT + (bid & (NCNT - 1))) * CNT_STRIDE, 1,
                __ATOMIC_RELAXED, __HIP_MEMORY_SCOPE_AGENT);
        // workers do NOT wait here; the wait happens at the top of the next
        // iteration (and not at all after the last one).
    }

    // ---- final aggregate by block 0 (replaces kmeans_finalize) ----
    if (bid == 0) {
        if (tid < NCNT) {
            int* cptr = barCnt + ((size_t)(N_ITER - 1) * NCNT + tid) * CNT_STRIDE;
            while (__hip_atomic_load(cptr, __ATOMIC_RELAXED,
                                     __HIP_MEMORY_SCOPE_AGENT) < ARRIVE_DEPTH)
                __builtin_amdgcn_s_sleep(2);
        }
        __syncthreads();
        out[tid] = sum32_if(shards + (size_t)(N_ITER - 1) * K * SLOTS, tid);
    }
}

// ---------------- fallback path (if cooperative launch unavailable) ----------------
__global__ __launch_bounds__(TPB) void kmeans_step(
    const float* __restrict__ cur0,
    const float* __restrict__ prevShards,
    const float* __restrict__ heatmap,
    float* __restrict__ outShards)
{
    __shared__ float2 cls[C];
    __shared__ float2 cand[C];
    __shared__ int    candIdx[C];
    __shared__ float  waveMin[2];
    __shared__ int    waveCnt[2];
    __shared__ float  acc[SLOTS];
    __shared__ unsigned char dupf[C];

    const int tid   = threadIdx.x;
    const int tileR = (blockIdx.x >> 5) * TILE;
    const int tileC = (blockIdx.x & 31) * TILE;

    acc[tid] = 0.0f;
    if (tid < C) dupf[tid] = 0;

    float coord;
    if (prevShards) {
        float s = 0.0f;
#pragma unroll
        for (int k = 0; k < K; ++k) s += prevShards[k * SLOTS + tid];
        coord = s;
    } else {
        coord = cur0[tid];
    }
    ((float*)cls)[tid] = coord;
    __syncthreads();

    const int    di  = tid & (C - 1);
    const float2 dme = cls[di];

    float dcen = 0.0f;
    if (tid < C) {
        const float dxr = dme.x - ((float)tileR + 15.5f);
        const float dyc = dme.y - ((float)tileC + 15.5f);
        dcen = sqrtf(dxr * dxr + dyc * dyc);
        float m = dcen;
#pragma unroll
        for (int off = 32; off > 0; off >>= 1)
            m = fminf(m, __shfl_xor(m, off));
        if ((tid & 63) == 0) waveMin[tid >> 6] = m;
    }
    {
        const int kLo = (tid < C) ? 1 : 33;
#pragma unroll 8
        for (int kk = 0; kk < 32; ++kk) {
            const int k = kLo + kk;
            const int j = (di + k) & (C - 1);
            const float2 o = cls[j];
            if (o.x == dme.x && o.y == dme.y)
                dupf[(di + k < C) ? (di + k) : di] = 1;
        }
    }
    __syncthreads();

    bool keep = false;
    int  pre  = 0;
    if (tid < C) {
        const float thr = fminf(waveMin[0], waveMin[1]) + 44.84062f;
        keep = (dcen <= thr) && (dupf[tid] == 0);
        const unsigned long long mask = __ballot(keep);
        const int lane = tid & 63;
        pre = __popcll(mask & ((1ull << lane) - 1ull));
        if (lane == 0) waveCnt[tid >> 6] = __popcll(mask);
    }
    __syncthreads();
    if (keep) {
        const int pos = pre + ((tid >= 64) ? waveCnt[0] : 0);
        cand[pos]    = cls[tid];
        candIdx[pos] = tid;
    }
    __syncthreads();

    const int nCand = waveCnt[0] + waveCnt[1];

    const int   rowIn = tid >> 3;
    const float fr    = (float)(tileR + rowIn);
    const int   col0  = tileC + (tid & 7) * PPT;
    const float4 h4   = *(const float4*)(heatmap + (size_t)(tileR + rowIn) * W + col0);

    float hval[PPT] = { h4.x, h4.y, h4.z, h4.w };
    float colf[PPT], best[PPT];
    int   bi[PPT];
#pragma unroll
    for (int p = 0; p < PPT; ++p) {
        colf[p] = (float)(col0 + p);
        best[p] = FLT_MAX;
        bi[p]   = 0;
    }

    for (int k = 0; k < nCand; ++k) {
        const float2 cl = cand[k];
        const int    ci = candIdx[k];
        const float  dx  = fr - cl.x;
        const float  dx2 = dx * dx;
#pragma unroll
        for (int p = 0; p < PPT; ++p) {
            const float dy  = colf[p] - cl.y;
            const float d2  = fmaf(dy, dy, dx2);
            const float key = fmaxf(d2, 1.0f);
            const bool  lt  = key < best[p];
            bi[p]   = lt ? ci  : bi[p];
            best[p] = lt ? key : best[p];
        }
    }

#pragma unroll
    for (int p = 0; p < PPT; ++p) {
        const float bd  = fmaxf(1.0f, sqrtf(best[p]));
        const float wgt = hval[p] / bd;
        float v0 = fr      * wgt;
        float v1 = colf[p] * wgt;
        const int b0 = __shfl(bi[p], 0);
        if (__ballot(bi[p] == b0) == 0xFFFFFFFFFFFFFFFFull) {
#pragma unroll
            for (int off = 32; off > 0; off >>= 1) {
                v0 += __shfl_xor(v0, off);
                v1 += __shfl_xor(v1, off);
            }
            if ((tid & 63) == 0) {
                unsafeAtomicAdd(&acc[2 * b0 + 0], v0);
                unsafeAtomicAdd(&acc[2 * b0 + 1], v1);
            }
        } else {
            unsafeAtomicAdd(&acc[2 * bi[p] + 0], v0);
            unsafeAtomicAdd(&acc[2 * bi[p] + 1], v1);
        }
    }
    __syncthreads();

    const float a = acc[tid];
    if (a != 0.0f)
        unsafeAtomicAdd(&outShards[(blockIdx.x & (K - 1)) * SLOTS + tid], a);
}

__global__ __launch_bounds__(SLOTS) void kmeans_finalize(
    const float* __restrict__ shards,
    float* __restrict__ out)
{
    const int tid = threadIdx.x;
    float s = 0.0f;
#pragma unroll
    for (int k = 0; k < K; ++k) s += shards[k * SLOTS + tid];
    out[tid] = s;
}

extern "C" void kernel_launch(void* const* d_in, const int* in_sizes, int n_in,
                              void* d_out, int out_size, void* d_ws, size_t ws_size,
                              hipStream_t stream) {
    const float* clusters = (const float*)d_in[0];  // [C,2] = 256 floats
    const float* heatmap  = (const float*)d_in[1];  // [H,W] = 1M floats
    float* out = (float*)d_out;                     // [C,2] = 256 floats

    // d_ws layout: [N_ITER][K][SLOTS] shard floats (256 KB),
    //              [N_ITER][NCNT*CNT_STRIDE] barrier ints (64 KB),
    //              [N_ITER][CNT_STRIDE] flag ints (512 B),
    //              [N_ITER][SLOTS] published cluster coords (8 KB)
    float* shards = (float*)d_ws;
    const size_t shardBytes = (size_t)N_ITER * K * SLOTS * sizeof(float);
    int* barCnt = (int*)((char*)d_ws + shardBytes);
    const size_t cntBytes = (size_t)N_ITER * NCNT * CNT_STRIDE * sizeof(int);
    int* flags = (int*)((char*)barCnt + cntBytes);
    const size_t flagBytes = (size_t)N_ITER * CNT_STRIDE * sizeof(int);
    float* clsPub = (float*)((char*)flags + flagBytes);
    const size_t pubBytes = (size_t)N_ITER * SLOTS * sizeof(float);

    // zero shards + barrier state (harness re-poisons d_ws before every launch)
    hipMemsetAsync(d_ws, 0, shardBytes + cntBytes + flagBytes + pubBytes, stream);

    void* kargs[] = { (void*)&clusters, (void*)&heatmap, (void*)&shards,
                      (void*)&barCnt,   (void*)&flags,   (void*)&clsPub,
                      (void*)&out };
    hipError_t e = hipLaunchCooperativeKernel((const void*)kmeans_fused,
                                              dim3(NBLK), dim3(TPB),
                                              kargs, 0, stream);
    if (e != hipSuccess) {
        (void)hipGetLastError();   // clear sticky error; use multi-dispatch fallback
        const size_t perIter = (size_t)K * SLOTS;
        for (int it = 0; it < N_ITER; ++it) {
            const float* prev = (it == 0) ? nullptr : (shards + (it - 1) * perIter);
            float* dst = shards + it * perIter;
            kmeans_step<<<NBLK, TPB, 0, stream>>>(clusters, prev, heatmap, dst);
        }
        kmeans_finalize<<<1, SLOTS, 0, stream>>>(shards + (N_ITER - 1) * perIter, out);
    }
}

// Round 5
// 164.933 us; speedup vs baseline: 6.4026x; 1.0603x over previous
//
#include <hip/hip_runtime.h>
#include <float.h>

// Problem constants (match reference)
constexpr int H = 1024, W = 1024, C = 128, N_ITER = 8;
constexpr int TPB = 256;          // threads per block
constexpr int TILE = 32;          // 32x32 pixel tile per block
constexpr int PPT = 4;            // pixels (consecutive cols) per thread
constexpr int K = 32;             // atomic shards (contention depth 1024/K = 32)
constexpr int SLOTS = 2 * C;      // 256 accumulator slots
constexpr int NBLK = (H / TILE) * (W / TILE);   // 1024 blocks
constexpr int NCNT = 128;         // barrier arrival counters (depth 8 each)
constexpr int CNT_STRIDE = 16;    // ints between counters (64B apart)
constexpr int ARRIVE_DEPTH = NBLK / NCNT;       // 8
constexpr int NREP = 16;          // publish replicas (spread poll read traffic)
constexpr unsigned SIGNB = 0x80000000u;

// Round-3 lesson: atomic-contention-bound -> 32-way output sharding (kept).
// Round-4 lesson: O(C) dependent-LDS dedup chain -> parallel scan (now moved
//   to block 0 only — dedup depends ONLY on cluster data, identical for all
//   1024 blocks; it was computed redundantly 1024x).
// Round-5/6 lesson: grid-barrier congestion collapse from ~131K agent-scope
//   polling lanes (every poll = an IF transaction). Fixed in round 7 with
//   ONE poller/block + zero __threadfence: fused dispatch 983 -> 99.7us.
// Round-8 (this round): compress the barrier's serial fabric-hop chain.
//   Old release chain per iter: block0 wake -> 4 SERIAL groups of 8 bypass
//   loads (~1.6us) -> publish+ack -> flag poll -> clsPub load = ~4 hops.
//   New: (a) all 32 sum loads issued before one wait (1 round trip);
//   (b) publish encoded coords bits(v)^SIGN (always nonzero since v>=+0.0,
//       +inf/-0.0 included) into 16 replicas; workers poll THEIR OWN data
//       slot (wave ballot until all 64 lanes nonzero) -> flag hop AND the
//       second data load are gone; (c) block 0 computes the coincident-
//       cluster dup mask once and publishes dups as +inf -> dcen=inf ->
//       pruned exactly like the old per-block dup flag (lowest twin keeps
//       the true coords, so waveMin and the keep-set are unchanged ->
//       bit-identical). Workers drop the scan + one __syncthreads.
//       Iter-0 scan dropped too: ascending candIdx + strict '<' already
//       tie-breaks coincident clusters to the lowest index (the scan was
//       only a perf guard against candidate bloat, which block 0 now
//       provides for it>=1).
__device__ __forceinline__ void waitVmem() {
    asm volatile("s_waitcnt vmcnt(0)" ::: "memory");
}

__global__ __launch_bounds__(TPB, 4) void kmeans_fused(
    const float* __restrict__ cur0,        // [SLOTS] input clusters
    const float* __restrict__ heatmap,     // [H,W]
    float* __restrict__ shards,            // [N_ITER][K][SLOTS] (pre-zeroed)
    int*   __restrict__ barCnt,            // [N_ITER][NCNT*CNT_STRIDE] (pre-zeroed)
    unsigned* __restrict__ clsPub,         // [N_ITER][NREP][SLOTS] (pre-zeroed)
    float* __restrict__ out)               // [SLOTS]
{
    __shared__ float2 cls[C];              // aliased as float[SLOTS]
    __shared__ float2 cand[C];
    __shared__ int    candIdx[C];
    __shared__ float  waveMin[2];
    __shared__ int    waveCnt[2];
    __shared__ float  acc[SLOTS];          // SLOTS == 256 == TPB
    __shared__ unsigned char dupf[C];      // block 0 only

    const int tid   = threadIdx.x;
    const int bid   = blockIdx.x;
    const int tileR = (bid >> 5) * TILE;
    const int tileC = (bid & 31) * TILE;

    // ---- one-time pixel setup (amortized over 8 iters) ----
    const int   rowIn = tid >> 3;                         // 0..31
    const float fr    = (float)(tileR + rowIn);
    const int   col0  = tileC + (tid & 7) * PPT;
    const float4 h4   = *(const float4*)(heatmap + (size_t)(tileR + rowIn) * W + col0);
    float hval[PPT] = { h4.x, h4.y, h4.z, h4.w };
    float colf[PPT];
#pragma unroll
    for (int p = 0; p < PPT; ++p) colf[p] = (float)(col0 + p);

    for (int it = 0; it < N_ITER; ++it) {
        // ---- obtain this iteration's cluster coords ----
        float coord;
        if (it == 0) {
            coord = cur0[tid];
        } else {
            const int prevIt = it - 1;
            if (bid == 0) {
                // wake: 128 lanes poll 128 arrival counters (agent loads)
                if (tid < NCNT) {
                    int* cptr = barCnt + ((size_t)prevIt * NCNT + tid) * CNT_STRIDE;
                    while (__hip_atomic_load(cptr, __ATOMIC_RELAXED,
                                             __HIP_MEMORY_SCOPE_AGENT) < ARRIVE_DEPTH)
                        __builtin_amdgcn_s_sleep(2);
                }
                __syncthreads();
                // sum 32 shards: all 32 bypass loads in flight, ~1 round trip;
                // adds keep the exact k-ascending association.
                const float* b = shards + (size_t)prevIt * K * SLOTS + tid;
                float v[K];
#pragma unroll
                for (int k = 0; k < K; ++k)
                    v[k] = __hip_atomic_load(b + (size_t)k * SLOTS,
                                             __ATOMIC_RELAXED, __HIP_MEMORY_SCOPE_AGENT);
                float s = 0.0f;
#pragma unroll
                for (int k = 0; k < K; ++k) s += v[k];

                // dup scan once (cluster data identical for every block)
                if (tid < C) dupf[tid] = 0;
                ((float*)cls)[tid] = s;
                __syncthreads();
                {
                    const int    sdi  = tid & (C - 1);
                    const float2 sdme = cls[sdi];
                    const int kLo = (tid < C) ? 1 : 33;
#pragma unroll 8
                    for (int kk = 0; kk < 32; ++kk) {
                        const int k = kLo + kk;
                        const int j = (sdi + k) & (C - 1);
                        const float2 o = cls[j];
                        if (o.x == sdme.x && o.y == sdme.y)
                            dupf[(sdi + k < C) ? (sdi + k) : sdi] = 1;  // higher idx
                    }
                }
                __syncthreads();
                // poison dups with +inf (lowest twin keeps true coords) and
                // publish encoded (always-nonzero) value to NREP replicas
                const float pv = dupf[tid >> 1] ? (float)INFINITY : s;
                const unsigned enc = __float_as_uint(pv) ^ SIGNB;
                unsigned* pb = clsPub + (size_t)prevIt * NREP * SLOTS;
#pragma unroll
                for (int r = 0; r < NREP; ++r)
                    __hip_atomic_store(pb + r * SLOTS + tid, enc,
                                       __ATOMIC_RELAXED, __HIP_MEMORY_SCOPE_AGENT);
                coord = pv;
            } else {
                // workers: poll OWN data slot of replica bid&15 until nonzero
                const unsigned* src = clsPub
                    + ((size_t)prevIt * NREP + (bid & (NREP - 1))) * SLOTS;
                unsigned u;
                for (;;) {
                    u = __hip_atomic_load(src + tid, __ATOMIC_RELAXED,
                                          __HIP_MEMORY_SCOPE_AGENT);
                    if (__ballot(u != 0u) == 0xFFFFFFFFFFFFFFFFull) break;
                    __builtin_amdgcn_s_sleep(4);
                }
                coord = __uint_as_float(u ^ SIGNB);
            }
        }

        // ---- phase 0: coords into LDS ----
        acc[tid] = 0.0f;
        ((float*)cls)[tid] = coord;
        __syncthreads();

        // ---- phase 1a: center-distance + wave min (threads 0..127) ----
        float dcen = 0.0f;
        if (tid < C) {
            const float2 cl = cls[tid];
            const float dxr = cl.x - ((float)tileR + 15.5f);
            const float dyc = cl.y - ((float)tileC + 15.5f);
            dcen = sqrtf(dxr * dxr + dyc * dyc);    // +inf for poisoned dups
            float m = dcen;
#pragma unroll
            for (int off = 32; off > 0; off >>= 1)
                m = fminf(m, __shfl_xor(m, off));
            if ((tid & 63) == 0) waveMin[tid >> 6] = m;
        }
        __syncthreads();

        // ---- phase 1b: prune + ballot prefix (order-preserving) ----
        bool keep = false;
        int  pre  = 0;
        if (tid < C) {
            // 2*r_tile = 2*15.5*sqrt(2) = 43.84062; +1.0 clamp/rounding margin
            const float thr = fminf(waveMin[0], waveMin[1]) + 44.84062f;
            keep = (dcen <= thr);                   // inf-poisoned dups fail
            const unsigned long long mask = __ballot(keep);
            const int lane = tid & 63;
            pre = __popcll(mask & ((1ull << lane) - 1ull));
            if (lane == 0) waveCnt[tid >> 6] = __popcll(mask);
        }
        __syncthreads();
        if (keep) {
            const int pos = pre + ((tid >= 64) ? waveCnt[0] : 0);
            cand[pos]    = cls[tid];
            candIdx[pos] = tid;
        }
        __syncthreads();

        const int nCand = waveCnt[0] + waveCnt[1];   // >= 1 always

        // ---- phase 2: pruned argmin over candidates ----
        float best[PPT];
        int   bi[PPT];
#pragma unroll
        for (int p = 0; p < PPT; ++p) { best[p] = FLT_MAX; bi[p] = 0; }

        for (int k = 0; k < nCand; ++k) {
            const float2 cl = cand[k];                    // wave-uniform broadcast
            const int    ci = candIdx[k];
            const float  dx  = fr - cl.x;
            const float  dx2 = dx * dx;                   // row-constant, reused x4
#pragma unroll
            for (int p = 0; p < PPT; ++p) {
                const float dy  = colf[p] - cl.y;
                const float d2  = fmaf(dy, dy, dx2);
                const float key = fmaxf(d2, 1.0f);        // clamp before compare
                const bool  lt  = key < best[p];          // strict <: first-index ties
                bi[p]   = lt ? ci  : bi[p];
                best[p] = lt ? key : best[p];
            }
        }

        // ---- epilogue: wave-uniform reduce fast path; LDS scatter ----
#pragma unroll
        for (int p = 0; p < PPT; ++p) {
            const float bd  = fmaxf(1.0f, sqrtf(best[p]));  // = max(1, sqrt(d2))
            const float wgt = hval[p] / bd;
            float v0 = fr      * wgt;
            float v1 = colf[p] * wgt;
            const int b0 = __shfl(bi[p], 0);
            if (__ballot(bi[p] == b0) == 0xFFFFFFFFFFFFFFFFull) {
#pragma unroll
                for (int off = 32; off > 0; off >>= 1) {
                    v0 += __shfl_xor(v0, off);
                    v1 += __shfl_xor(v1, off);
                }
                if ((tid & 63) == 0) {
                    unsafeAtomicAdd(&acc[2 * b0 + 0], v0);
                    unsafeAtomicAdd(&acc[2 * b0 + 1], v1);
                }
            } else {
                unsafeAtomicAdd(&acc[2 * bi[p] + 0], v0);
                unsafeAtomicAdd(&acc[2 * bi[p] + 1], v1);
            }
        }
        __syncthreads();

        // one global atomic per NONZERO slot into this block's shard.
        // (device-scope atomic, performed at the coherence point — m20)
        const float a = acc[tid];
        if (a != 0.0f)
            unsafeAtomicAdd(&shards[(size_t)it * K * SLOTS
                                    + (bid & (K - 1)) * SLOTS + tid], a);

        // ---- arrive (fence-free): my atomics ack'd, then relaxed add ----
        waitVmem();
        __syncthreads();
        if (tid == 0)
            __hip_atomic_fetch_add(
                barCnt + ((size_t)it * NCNT + (bid & (NCNT - 1))) * CNT_STRIDE, 1,
                __ATOMIC_RELAXED, __HIP_MEMORY_SCOPE_AGENT);
        // workers do NOT wait here; the wait is at the top of the next
        // iteration (and not at all after the last one).
    }

    // ---- final aggregate by block 0 (replaces kmeans_finalize) ----
    if (bid == 0) {
        if (tid < NCNT) {
            int* cptr = barCnt + ((size_t)(N_ITER - 1) * NCNT + tid) * CNT_STRIDE;
            while (__hip_atomic_load(cptr, __ATOMIC_RELAXED,
                                     __HIP_MEMORY_SCOPE_AGENT) < ARRIVE_DEPTH)
                __builtin_amdgcn_s_sleep(2);
        }
        __syncthreads();
        const float* b = shards + (size_t)(N_ITER - 1) * K * SLOTS + tid;
        float v[K];
#pragma unroll
        for (int k = 0; k < K; ++k)
            v[k] = __hip_atomic_load(b + (size_t)k * SLOTS,
                                     __ATOMIC_RELAXED, __HIP_MEMORY_SCOPE_AGENT);
        float s = 0.0f;
#pragma unroll
        for (int k = 0; k < K; ++k) s += v[k];
        out[tid] = s;
    }
}

// ---------------- fallback path (if cooperative launch unavailable) ----------------
__global__ __launch_bounds__(TPB) void kmeans_step(
    const float* __restrict__ cur0,
    const float* __restrict__ prevShards,
    const float* __restrict__ heatmap,
    float* __restrict__ outShards)
{
    __shared__ float2 cls[C];
    __shared__ float2 cand[C];
    __shared__ int    candIdx[C];
    __shared__ float  waveMin[2];
    __shared__ int    waveCnt[2];
    __shared__ float  acc[SLOTS];
    __shared__ unsigned char dupf[C];

    const int tid   = threadIdx.x;
    const int tileR = (blockIdx.x >> 5) * TILE;
    const int tileC = (blockIdx.x & 31) * TILE;

    acc[tid] = 0.0f;
    if (tid < C) dupf[tid] = 0;

    float coord;
    if (prevShards) {
        float s = 0.0f;
#pragma unroll
        for (int k = 0; k < K; ++k) s += prevShards[k * SLOTS + tid];
        coord = s;
    } else {
        coord = cur0[tid];
    }
    ((float*)cls)[tid] = coord;
    __syncthreads();

    const int    di  = tid & (C - 1);
    const float2 dme = cls[di];

    float dcen = 0.0f;
    if (tid < C) {
        const float dxr = dme.x - ((float)tileR + 15.5f);
        const float dyc = dme.y - ((float)tileC + 15.5f);
        dcen = sqrtf(dxr * dxr + dyc * dyc);
        float m = dcen;
#pragma unroll
        for (int off = 32; off > 0; off >>= 1)
            m = fminf(m, __shfl_xor(m, off));
        if ((tid & 63) == 0) waveMin[tid >> 6] = m;
    }
    {
        const int kLo = (tid < C) ? 1 : 33;
#pragma unroll 8
        for (int kk = 0; kk < 32; ++kk) {
            const int k = kLo + kk;
            const int j = (di + k) & (C - 1);
            const float2 o = cls[j];
            if (o.x == dme.x && o.y == dme.y)
                dupf[(di + k < C) ? (di + k) : di] = 1;
        }
    }
    __syncthreads();

    bool keep = false;
    int  pre  = 0;
    if (tid < C) {
        const float thr = fminf(waveMin[0], waveMin[1]) + 44.84062f;
        keep = (dcen <= thr) && (dupf[tid] == 0);
        const unsigned long long mask = __ballot(keep);
        const int lane = tid & 63;
        pre = __popcll(mask & ((1ull << lane) - 1ull));
        if (lane == 0) waveCnt[tid >> 6] = __popcll(mask);
    }
    __syncthreads();
    if (keep) {
        const int pos = pre + ((tid >= 64) ? waveCnt[0] : 0);
        cand[pos]    = cls[tid];
        candIdx[pos] = tid;
    }
    __syncthreads();

    const int nCand = waveCnt[0] + waveCnt[1];

    const int   rowIn = tid >> 3;
    const float fr    = (float)(tileR + rowIn);
    const int   col0  = tileC + (tid & 7) * PPT;
    const float4 h4   = *(const float4*)(heatmap + (size_t)(tileR + rowIn) * W + col0);

    float hval[PPT] = { h4.x, h4.y, h4.z, h4.w };
    float colf[PPT], best[PPT];
    int   bi[PPT];
#pragma unroll
    for (int p = 0; p < PPT; ++p) {
        colf[p] = (float)(col0 + p);
        best[p] = FLT_MAX;
        bi[p]   = 0;
    }

    for (int k = 0; k < nCand; ++k) {
        const float2 cl = cand[k];
        const int    ci = candIdx[k];
        const float  dx  = fr - cl.x;
        const float  dx2 = dx * dx;
#pragma unroll
        for (int p = 0; p < PPT; ++p) {
            const float dy  = colf[p] - cl.y;
            const float d2  = fmaf(dy, dy, dx2);
            const float key = fmaxf(d2, 1.0f);
            const bool  lt  = key < best[p];
            bi[p]   = lt ? ci  : bi[p];
            best[p] = lt ? key : best[p];
        }
    }

#pragma unroll
    for (int p = 0; p < PPT; ++p) {
        const float bd  = fmaxf(1.0f, sqrtf(best[p]));
        const float wgt = hval[p] / bd;
        float v0 = fr      * wgt;
        float v1 = colf[p] * wgt;
        const int b0 = __shfl(bi[p], 0);
        if (__ballot(bi[p] == b0) == 0xFFFFFFFFFFFFFFFFull) {
#pragma unroll
            for (int off = 32; off > 0; off >>= 1) {
                v0 += __shfl_xor(v0, off);
                v1 += __shfl_xor(v1, off);
            }
            if ((tid & 63) == 0) {
                unsafeAtomicAdd(&acc[2 * b0 + 0], v0);
                unsafeAtomicAdd(&acc[2 * b0 + 1], v1);
            }
        } else {
            unsafeAtomicAdd(&acc[2 * bi[p] + 0], v0);
            unsafeAtomicAdd(&acc[2 * bi[p] + 1], v1);
        }
    }
    __syncthreads();

    const float a = acc[tid];
    if (a != 0.0f)
        unsafeAtomicAdd(&outShards[(blockIdx.x & (K - 1)) * SLOTS + tid], a);
}

__global__ __launch_bounds__(SLOTS) void kmeans_finalize(
    const float* __restrict__ shards,
    float* __restrict__ out)
{
    const int tid = threadIdx.x;
    float s = 0.0f;
#pragma unroll
    for (int k = 0; k < K; ++k) s += shards[k * SLOTS + tid];
    out[tid] = s;
}

extern "C" void kernel_launch(void* const* d_in, const int* in_sizes, int n_in,
                              void* d_out, int out_size, void* d_ws, size_t ws_size,
                              hipStream_t stream) {
    const float* clusters = (const float*)d_in[0];  // [C,2] = 256 floats
    const float* heatmap  = (const float*)d_in[1];  // [H,W] = 1M floats
    float* out = (float*)d_out;                     // [C,2] = 256 floats

    // d_ws layout: [N_ITER][K][SLOTS] shard floats (256 KB),
    //              [N_ITER][NCNT*CNT_STRIDE] barrier ints (64 KB),
    //              [N_ITER][NREP][SLOTS] encoded publish replicas (128 KB)
    float* shards = (float*)d_ws;
    const size_t shardBytes = (size_t)N_ITER * K * SLOTS * sizeof(float);
    int* barCnt = (int*)((char*)d_ws + shardBytes);
    const size_t cntBytes = (size_t)N_ITER * NCNT * CNT_STRIDE * sizeof(int);
    unsigned* clsPub = (unsigned*)((char*)barCnt + cntBytes);
    const size_t pubBytes = (size_t)N_ITER * NREP * SLOTS * sizeof(unsigned);

    // zero shards + barrier + publish state (harness re-poisons d_ws each launch)
    hipMemsetAsync(d_ws, 0, shardBytes + cntBytes + pubBytes, stream);

    void* kargs[] = { (void*)&clusters, (void*)&heatmap, (void*)&shards,
                      (void*)&barCnt,   (void*)&clsPub,  (void*)&out };
    hipError_t e = hipLaunchCooperativeKernel((const void*)kmeans_fused,
                                              dim3(NBLK), dim3(TPB),
                                              kargs, 0, stream);
    if (e != hipSuccess) {
        (void)hipGetLastError();   // clear sticky error; use multi-dispatch fallback
        const size_t perIter = (size_t)K * SLOTS;
        for (int it = 0; it < N_ITER; ++it) {
            const float* prev = (it == 0) ? nullptr : (shards + (it - 1) * perIter);
            float* dst = shards + it * perIter;
            kmeans_step<<<NBLK, TPB, 0, stream>>>(clusters, prev, heatmap, dst);
        }
        kmeans_finalize<<<1, SLOTS, 0, stream>>>(shards + (N_ITER - 1) * perIter, out);
    }
}

// Round 6
// 141.589 us; speedup vs baseline: 7.4582x; 1.1649x over previous
//
#include <hip/hip_runtime.h>
#include <float.h>

// Problem constants (match reference)
constexpr int H = 1024, W = 1024, C = 128, N_ITER = 8;
constexpr int TPB = 256;          // threads per block
constexpr int TILE = 32;          // 32x32 pixel tile per block
constexpr int PPT = 4;            // pixels (consecutive cols) per thread
constexpr int K = 32;             // atomic shards (contention depth 1024/K = 32)
constexpr int SLOTS = 2 * C;      // 256 accumulator slots
constexpr int NBLK = (H / TILE) * (W / TILE);   // 1024 WORKER blocks (grid = NBLK+1)
constexpr int NCNT = 128;         // barrier arrival counters (depth 8 each)
constexpr int CNT_STRIDE = 16;    // ints between counters (64B apart)
constexpr int ARRIVE_DEPTH = NBLK / NCNT;       // 8
constexpr int NREP = 16;          // publish replicas (spread poll read traffic)
constexpr unsigned SIGNB = 0x80000000u;

// Ledger of locked-in lessons:
// R3: atomic-contention-bound -> 32-way output sharding.
// R4: O(C) dependent-LDS dedup chain -> parallel all-pairs scan.
// R5/6: grid-barrier congestion collapse from ~131K agent-scope pollers;
//   fixed with ONE poller/block + zero __threadfence (983 -> 99.7us).
// R8: hop compression: batched 32-load shard sum, self-announcing encoded
//   publish (bits^SIGN, poll your own data slot), dedup computed ONCE on the
//   aggregator and exported as +inf poisoning (99.7 -> 89.5us; LDS bank
//   conflicts 3.67M -> 3.3K).
// R9 (this round):
//   (a) REGULAR launch instead of hipLaunchCooperativeKernel: totals across
//       rounds isolate ~33us of coop-dispatch overhead (165-40-2-89.5).
//       Nothing uses coop APIs — the barrier is hand-rolled. Co-residency
//       is guaranteed by capacity: 1025 blocks x 4 waves x <=64 VGPR x
//       4.3KB LDS => >=8 blocks/CU possible, 1025/256 needs only 5.
//   (b) DEDICATED aggregator block (bid 0, no tile): polls arrival counters
//       continuously during the compute phase (sleep(1)), so detect happens
//       ~1 fabric-RT after the last arrival instead of after block-0's own
//       tile compute. Workers are bid 1..NBLK, wid = bid-1. Final out write
//       also on the aggregator. All arithmetic/order bit-identical.
__device__ __forceinline__ void waitVmem() {
    asm volatile("s_waitcnt vmcnt(0)" ::: "memory");
}

__global__ __launch_bounds__(TPB, 4) void kmeans_fused(
    const float* __restrict__ cur0,        // [SLOTS] input clusters
    const float* __restrict__ heatmap,     // [H,W]
    float* __restrict__ shards,            // [N_ITER][K][SLOTS] (pre-zeroed)
    int*   __restrict__ barCnt,            // [N_ITER][NCNT*CNT_STRIDE] (pre-zeroed)
    unsigned* __restrict__ clsPub,         // [N_ITER][NREP][SLOTS] (pre-zeroed)
    float* __restrict__ out)               // [SLOTS]
{
    __shared__ float2 cls[C];              // aliased as float[SLOTS]
    __shared__ float2 cand[C];
    __shared__ int    candIdx[C];
    __shared__ float  waveMin[2];
    __shared__ int    waveCnt[2];
    __shared__ float  acc[SLOTS];          // SLOTS == 256 == TPB
    __shared__ unsigned char dupf[C];      // aggregator only

    const int tid = threadIdx.x;
    const int bid = blockIdx.x;

    // ================= dedicated aggregator (no tile work) =================
    if (bid == 0) {
        for (int it = 0; it < N_ITER; ++it) {
            // wake: 128 lanes poll 128 arrival counters, tight sleep
            if (tid < NCNT) {
                int* cptr = barCnt + ((size_t)it * NCNT + tid) * CNT_STRIDE;
                while (__hip_atomic_load(cptr, __ATOMIC_RELAXED,
                                         __HIP_MEMORY_SCOPE_AGENT) < ARRIVE_DEPTH)
                    __builtin_amdgcn_s_sleep(1);
            }
            __syncthreads();

            // sum 32 shards: all bypass loads in flight (~1 round trip);
            // adds keep the exact k-ascending association.
            const float* b = shards + (size_t)it * K * SLOTS + tid;
            float v[K];
#pragma unroll
            for (int k = 0; k < K; ++k)
                v[k] = __hip_atomic_load(b + (size_t)k * SLOTS,
                                         __ATOMIC_RELAXED, __HIP_MEMORY_SCOPE_AGENT);
            float s = 0.0f;
#pragma unroll
            for (int k = 0; k < K; ++k) s += v[k];

            if (it == N_ITER - 1) {        // final: write result, done
                out[tid] = s;
                return;
            }

            // dup scan once (cluster data identical for every block)
            if (tid < C) dupf[tid] = 0;
            ((float*)cls)[tid] = s;
            __syncthreads();
            {
                const int    sdi  = tid & (C - 1);
                const float2 sdme = cls[sdi];
                const int kLo = (tid < C) ? 1 : 33;
#pragma unroll 8
                for (int kk = 0; kk < 32; ++kk) {
                    const int k = kLo + kk;
                    const int j = (sdi + k) & (C - 1);
                    const float2 o = cls[j];
                    if (o.x == sdme.x && o.y == sdme.y)
                        dupf[(sdi + k < C) ? (sdi + k) : sdi] = 1;  // higher idx
                }
            }
            __syncthreads();

            // poison dups with +inf (lowest twin keeps true coords) and
            // publish encoded (always-nonzero) value to NREP replicas
            const float pv = dupf[tid >> 1] ? (float)INFINITY : s;
            const unsigned enc = __float_as_uint(pv) ^ SIGNB;
            unsigned* pb = clsPub + (size_t)it * NREP * SLOTS;
#pragma unroll
            for (int r = 0; r < NREP; ++r)
                __hip_atomic_store(pb + r * SLOTS + tid, enc,
                                   __ATOMIC_RELAXED, __HIP_MEMORY_SCOPE_AGENT);
            // no wait: visibility rides the fabric while we go back to polling
        }
        return;
    }

    // ========================== worker blocks ==========================
    const int wid   = bid - 1;             // tile id 0..1023
    const int tileR = (wid >> 5) * TILE;
    const int tileC = (wid & 31) * TILE;

    // ---- one-time pixel setup (amortized over 8 iters) ----
    const int   rowIn = tid >> 3;                         // 0..31
    const float fr    = (float)(tileR + rowIn);
    const int   col0  = tileC + (tid & 7) * PPT;
    const float4 h4   = *(const float4*)(heatmap + (size_t)(tileR + rowIn) * W + col0);
    float hval[PPT] = { h4.x, h4.y, h4.z, h4.w };
    float colf[PPT];
#pragma unroll
    for (int p = 0; p < PPT; ++p) colf[p] = (float)(col0 + p);

    for (int it = 0; it < N_ITER; ++it) {
        // ---- obtain this iteration's cluster coords ----
        float coord;
        if (it == 0) {
            coord = cur0[tid];
        } else {
            // poll OWN data slot of replica wid&15 until nonzero
            const unsigned* src = clsPub
                + ((size_t)(it - 1) * NREP + (wid & (NREP - 1))) * SLOTS;
            unsigned u;
            for (;;) {
                u = __hip_atomic_load(src + tid, __ATOMIC_RELAXED,
                                      __HIP_MEMORY_SCOPE_AGENT);
                if (__ballot(u != 0u) == 0xFFFFFFFFFFFFFFFFull) break;
                __builtin_amdgcn_s_sleep(4);
            }
            coord = __uint_as_float(u ^ SIGNB);
        }

        // ---- phase 0: coords into LDS ----
        acc[tid] = 0.0f;
        ((float*)cls)[tid] = coord;
        __syncthreads();

        // ---- phase 1a: center-distance + wave min (threads 0..127) ----
        float dcen = 0.0f;
        if (tid < C) {
            const float2 cl = cls[tid];
            const float dxr = cl.x - ((float)tileR + 15.5f);
            const float dyc = cl.y - ((float)tileC + 15.5f);
            dcen = sqrtf(dxr * dxr + dyc * dyc);    // +inf for poisoned dups
            float m = dcen;
#pragma unroll
            for (int off = 32; off > 0; off >>= 1)
                m = fminf(m, __shfl_xor(m, off));
            if ((tid & 63) == 0) waveMin[tid >> 6] = m;
        }
        __syncthreads();

        // ---- phase 1b: prune + ballot prefix (order-preserving) ----
        bool keep = false;
        int  pre  = 0;
        if (tid < C) {
            // 2*r_tile = 2*15.5*sqrt(2) = 43.84062; +1.0 clamp/rounding margin
            const float thr = fminf(waveMin[0], waveMin[1]) + 44.84062f;
            keep = (dcen <= thr);                   // inf-poisoned dups fail
            const unsigned long long mask = __ballot(keep);
            const int lane = tid & 63;
            pre = __popcll(mask & ((1ull << lane) - 1ull));
            if (lane == 0) waveCnt[tid >> 6] = __popcll(mask);
        }
        __syncthreads();
        if (keep) {
            const int pos = pre + ((tid >= 64) ? waveCnt[0] : 0);
            cand[pos]    = cls[tid];
            candIdx[pos] = tid;
        }
        __syncthreads();

        const int nCand = waveCnt[0] + waveCnt[1];   // >= 1 always

        // ---- phase 2: pruned argmin over candidates ----
        float best[PPT];
        int   bi[PPT];
#pragma unroll
        for (int p = 0; p < PPT; ++p) { best[p] = FLT_MAX; bi[p] = 0; }

        for (int k = 0; k < nCand; ++k) {
            const float2 cl = cand[k];                    // wave-uniform broadcast
            const int    ci = candIdx[k];
            const float  dx  = fr - cl.x;
            const float  dx2 = dx * dx;                   // row-constant, reused x4
#pragma unroll
            for (int p = 0; p < PPT; ++p) {
                const float dy  = colf[p] - cl.y;
                const float d2  = fmaf(dy, dy, dx2);
                const float key = fmaxf(d2, 1.0f);        // clamp before compare
                const bool  lt  = key < best[p];          // strict <: first-index ties
                bi[p]   = lt ? ci  : bi[p];
                best[p] = lt ? key : best[p];
            }
        }

        // ---- epilogue: wave-uniform reduce fast path; LDS scatter ----
#pragma unroll
        for (int p = 0; p < PPT; ++p) {
            const float bd  = fmaxf(1.0f, sqrtf(best[p]));  // = max(1, sqrt(d2))
            const float wgt = hval[p] / bd;
            float v0 = fr      * wgt;
            float v1 = colf[p] * wgt;
            const int b0 = __shfl(bi[p], 0);
            if (__ballot(bi[p] == b0) == 0xFFFFFFFFFFFFFFFFull) {
#pragma unroll
                for (int off = 32; off > 0; off >>= 1) {
                    v0 += __shfl_xor(v0, off);
                    v1 += __shfl_xor(v1, off);
                }
                if ((tid & 63) == 0) {
                    unsafeAtomicAdd(&acc[2 * b0 + 0], v0);
                    unsafeAtomicAdd(&acc[2 * b0 + 1], v1);
                }
            } else {
                unsafeAtomicAdd(&acc[2 * bi[p] + 0], v0);
                unsafeAtomicAdd(&acc[2 * bi[p] + 1], v1);
            }
        }
        __syncthreads();

        // one global atomic per NONZERO slot into this block's shard.
        // (device-scope atomic, performed at the coherence point — m20)
        const float a = acc[tid];
        if (a != 0.0f)
            unsafeAtomicAdd(&shards[(size_t)it * K * SLOTS
                                    + (wid & (K - 1)) * SLOTS + tid], a);

        // ---- arrive (fence-free): my atomics ack'd, then relaxed add ----
        waitVmem();
        __syncthreads();
        if (tid == 0)
            __hip_atomic_fetch_add(
                barCnt + ((size_t)it * NCNT + (wid & (NCNT - 1))) * CNT_STRIDE, 1,
                __ATOMIC_RELAXED, __HIP_MEMORY_SCOPE_AGENT);
        // workers never wait at the bottom; the wait is the data poll at the
        // top of the next iteration (none after the last).
    }
}

extern "C" void kernel_launch(void* const* d_in, const int* in_sizes, int n_in,
                              void* d_out, int out_size, void* d_ws, size_t ws_size,
                              hipStream_t stream) {
    const float* clusters = (const float*)d_in[0];  // [C,2] = 256 floats
    const float* heatmap  = (const float*)d_in[1];  // [H,W] = 1M floats
    float* out = (float*)d_out;                     // [C,2] = 256 floats

    // d_ws layout: [N_ITER][K][SLOTS] shard floats (256 KB),
    //              [N_ITER][NCNT*CNT_STRIDE] barrier ints (64 KB),
    //              [N_ITER][NREP][SLOTS] encoded publish replicas (128 KB)
    float* shards = (float*)d_ws;
    const size_t shardBytes = (size_t)N_ITER * K * SLOTS * sizeof(float);
    int* barCnt = (int*)((char*)d_ws + shardBytes);
    const size_t cntBytes = (size_t)N_ITER * NCNT * CNT_STRIDE * sizeof(int);
    unsigned* clsPub = (unsigned*)((char*)barCnt + cntBytes);
    const size_t pubBytes = (size_t)N_ITER * NREP * SLOTS * sizeof(unsigned);

    // zero shards + barrier + publish state (harness re-poisons d_ws each launch)
    hipMemsetAsync(d_ws, 0, shardBytes + cntBytes + pubBytes, stream);

    // REGULAR launch (coop dispatch costs ~33us extra). Co-residency of all
    // NBLK+1 blocks is guaranteed by capacity: 4 waves/block, <=64 VGPR,
    // 4.3KB LDS -> >=8 blocks/CU; we need ceil(1025/256) = 5.
    kmeans_fused<<<NBLK + 1, TPB, 0, stream>>>(clusters, heatmap, shards,
                                               barCnt, clsPub, out);
}